// Round 5
// baseline (513.145 us; speedup 1.0000x reference)
//
#include <hip/hip_runtime.h>
#include <math.h>

#define EMBED 512
#define HD 256
#define FR 12
#define NV 64
#define NT_TOK 4096
#define NV_TOK 768
#define NBLK 256
#define MAGIC 0x13579BDF

// s_waitcnt immediates (gfx9): vmcnt[3:0], expcnt[6:4], lgkmcnt[11:8], vmcnt[5:4]@15:14
#define WAIT_VM4 0x0F74   // vmcnt<=4
#define WAIT_VM0 0x0F70   // vmcnt<=0

typedef __attribute__((ext_vector_type(8))) short short8;
typedef __attribute__((ext_vector_type(4))) float f32x4;

__device__ __forceinline__ unsigned int f2bf(float f) {
  unsigned int u = __float_as_uint(f);
  u += 0x7FFFu + ((u >> 16) & 1u);   // RNE
  return u >> 16;
}
__device__ __forceinline__ float bf2f(unsigned int h) {
  return __uint_as_float(h << 16);
}
__device__ __forceinline__ void async_cp16(void* lds, const void* g) {
  __builtin_amdgcn_global_load_lds(
      (const __attribute__((address_space(1))) void*)g,
      (__attribute__((address_space(3))) void*)lds, 16, 0, 0);
}

// ---- grid barrier: one counter slot per barrier, counts to NBLK -----------
__device__ __forceinline__ void gbar(int* sync, int idx) {
  __syncthreads();
  if (threadIdx.x == 0) {
    __threadfence();  // release: write-back so other XCDs see our stores
    __hip_atomic_fetch_add(&sync[idx], 1, __ATOMIC_ACQ_REL,
                           __HIP_MEMORY_SCOPE_AGENT);
    while (__hip_atomic_load(&sync[idx], __ATOMIC_ACQUIRE,
                             __HIP_MEMORY_SCOPE_AGENT) < NBLK)
      __builtin_amdgcn_s_sleep(8);
    __threadfence();  // acquire: invalidate L1/L2 stale lines
  }
  __syncthreads();
}

// ---- GEMM tile: 128x128 C, BK=64, 8 waves of 32x64, double-buffered -------
// A: [M][lda] bf16 k-contig; B: [N][ldb] bf16 k-contig. LDS XOR-swizzled.
// MODE 0: bf16 row-major out; 1: fp32 row-major out; 2: bf16 transposed out
// (C[col*ldc + row], for direct Vt).
template <int MODE>
__device__ void gemm_tile(
    const unsigned short* __restrict__ Ab, int lda,
    const unsigned short* __restrict__ Bb, int ldb,
    const float* __restrict__ bias, void* __restrict__ Cv, int ldc,
    int m0, int n0, int K,
    unsigned short (*As)[8192], unsigned short (*Bs)[8192]) {
  int tid = threadIdx.x;
  int w = tid >> 6, lane = tid & 63;
  int lr = lane & 15, quad = lane >> 4;
  int wm = (w & 3) * 32, wn = (w >> 2) * 64;
  int rowS[2], cgS[2];
  #pragma unroll
  for (int i = 0; i < 2; ++i) {
    int s = tid + i * 512;
    rowS[i] = s >> 3; cgS[i] = (s & 7) ^ (rowS[i] & 7);
  }
  f32x4 acc[2][4] = {};
  int nk = K >> 6;
  #pragma unroll
  for (int i = 0; i < 2; ++i) {
    async_cp16(&As[0][(tid + i * 512) * 8],
               Ab + (size_t)(m0 + rowS[i]) * lda + cgS[i] * 8);
    async_cp16(&Bs[0][(tid + i * 512) * 8],
               Bb + (size_t)(n0 + rowS[i]) * ldb + cgS[i] * 8);
  }
  for (int k = 0; k < nk; ++k) {
    int cur = k & 1;
    __builtin_amdgcn_s_barrier();  // tile k-1 consumers done
    if (k + 1 < nk) {
      int nxt = cur ^ 1, koff = (k + 1) << 6;
      #pragma unroll
      for (int i = 0; i < 2; ++i) {
        async_cp16(&As[nxt][(tid + i * 512) * 8],
                   Ab + (size_t)(m0 + rowS[i]) * lda + koff + cgS[i] * 8);
        async_cp16(&Bs[nxt][(tid + i * 512) * 8],
                   Bb + (size_t)(n0 + rowS[i]) * ldb + koff + cgS[i] * 8);
      }
      __builtin_amdgcn_s_waitcnt(WAIT_VM4);  // tile k landed; k+1 in flight
    } else {
      __builtin_amdgcn_s_waitcnt(WAIT_VM0);
    }
    __builtin_amdgcn_s_barrier();  // tile k visible block-wide
    #pragma unroll
    for (int kk = 0; kk < 2; ++kk) {
      int sw = ((kk * 4 + quad) ^ (lr & 7)) * 8;
      short8 a0 = *(const short8*)&As[cur][(wm + lr) * 64 + sw];
      short8 a1 = *(const short8*)&As[cur][(wm + 16 + lr) * 64 + sw];
      short8 b0 = *(const short8*)&Bs[cur][(wn + lr) * 64 + sw];
      short8 b1 = *(const short8*)&Bs[cur][(wn + 16 + lr) * 64 + sw];
      short8 b2 = *(const short8*)&Bs[cur][(wn + 32 + lr) * 64 + sw];
      short8 b3 = *(const short8*)&Bs[cur][(wn + 48 + lr) * 64 + sw];
      acc[0][0] = __builtin_amdgcn_mfma_f32_16x16x32_bf16(a0, b0, acc[0][0], 0, 0, 0);
      acc[0][1] = __builtin_amdgcn_mfma_f32_16x16x32_bf16(a0, b1, acc[0][1], 0, 0, 0);
      acc[0][2] = __builtin_amdgcn_mfma_f32_16x16x32_bf16(a0, b2, acc[0][2], 0, 0, 0);
      acc[0][3] = __builtin_amdgcn_mfma_f32_16x16x32_bf16(a0, b3, acc[0][3], 0, 0, 0);
      acc[1][0] = __builtin_amdgcn_mfma_f32_16x16x32_bf16(a1, b0, acc[1][0], 0, 0, 0);
      acc[1][1] = __builtin_amdgcn_mfma_f32_16x16x32_bf16(a1, b1, acc[1][1], 0, 0, 0);
      acc[1][2] = __builtin_amdgcn_mfma_f32_16x16x32_bf16(a1, b2, acc[1][2], 0, 0, 0);
      acc[1][3] = __builtin_amdgcn_mfma_f32_16x16x32_bf16(a1, b3, acc[1][3], 0, 0, 0);
    }
  }
  // epilogue: C/D layout col=lane&15, row=quad*4+reg
  #pragma unroll
  for (int j = 0; j < 4; ++j) {
    int col = n0 + wn + j * 16 + lr;
    float bv = bias ? bias[col] : 0.0f;
    #pragma unroll
    for (int i = 0; i < 2; ++i) {
      int rbase = m0 + wm + i * 16 + quad * 4;
      if (MODE == 2) {
        ushort4 pk;
        pk.x = (unsigned short)f2bf(acc[i][j][0] + bv);
        pk.y = (unsigned short)f2bf(acc[i][j][1] + bv);
        pk.z = (unsigned short)f2bf(acc[i][j][2] + bv);
        pk.w = (unsigned short)f2bf(acc[i][j][3] + bv);
        *(ushort4*)&((unsigned short*)Cv)[(size_t)col * ldc + rbase] = pk;
      } else {
        #pragma unroll
        for (int r = 0; r < 4; ++r) {
          float v = acc[i][j][r] + bv;
          if (MODE == 0)
            ((unsigned short*)Cv)[(size_t)(rbase + r) * ldc + col] =
                (unsigned short)f2bf(v);
          else
            ((float*)Cv)[(size_t)(rbase + r) * ldc + col] = v;
        }
      }
    }
  }
}

// ---- LayerNorm, one row per block, 512 threads, 1 elem each ---------------
__device__ __forceinline__ void ln_row512(
    const float* __restrict__ xr, const float* __restrict__ rr,
    const float* __restrict__ g, const float* __restrict__ b,
    float* __restrict__ outf, unsigned short* __restrict__ outb,
    float* sbuf) {
  int t = threadIdx.x;
  float v = xr[t];
  if (rr != nullptr) v += rr[t];
  float s = v, s2 = v * v;
  #pragma unroll
  for (int off = 32; off > 0; off >>= 1) {
    s += __shfl_down(s, off, 64);
    s2 += __shfl_down(s2, off, 64);
  }
  int wid = t >> 6;
  __syncthreads();  // sbuf reuse guard across consecutive rows
  if ((t & 63) == 0) { sbuf[wid] = s; sbuf[8 + wid] = s2; }
  __syncthreads();
  if (t == 0) {
    float a = 0.f, a2 = 0.f;
    #pragma unroll
    for (int i = 0; i < 8; ++i) { a += sbuf[i]; a2 += sbuf[8 + i]; }
    float mean = a * (1.0f / EMBED);
    float var = a2 * (1.0f / EMBED) - mean * mean;
    sbuf[16] = mean;
    sbuf[17] = rsqrtf(var + 1e-5f);
  }
  __syncthreads();
  float mean = sbuf[16], rstd = sbuf[17];
  float y = (v - mean) * rstd * g[t] + b[t];
  if (outf != nullptr) outf[t] = y;
  if (outb != nullptr) outb[t] = (unsigned short)f2bf(y);
}

// ---- the megakernel -------------------------------------------------------
__global__ __launch_bounds__(512, 2) void mega(
    const float* __restrict__ text, const float* __restrict__ video,
    const float* __restrict__ ln1_g, const float* __restrict__ ln1_b,
    const float* __restrict__ Wq, const float* __restrict__ bq,
    const float* __restrict__ Wk, const float* __restrict__ bk,
    const float* __restrict__ Wv, const float* __restrict__ bv,
    const float* __restrict__ Wo, const float* __restrict__ bo,
    const float* __restrict__ Wl, const float* __restrict__ bl,
    const float* __restrict__ ln2_g, const float* __restrict__ ln2_b,
    const float* __restrict__ ln3_g, const float* __restrict__ ln3_b,
    float* __restrict__ out, char* __restrict__ ws) {
  // 84 KB static LDS -> max 1 block/CU -> all 256 blocks co-resident
  __shared__ __align__(16) unsigned short As[2][8192];
  __shared__ __align__(16) unsigned short Bs[2][8192];
  __shared__ __align__(16) char scratch[20480];

  unsigned short* Wbf = (unsigned short*)ws;
  unsigned short* Wq_bf = Wbf + 0 * 262144;
  unsigned short* Wk_bf = Wbf + 1 * 262144;
  unsigned short* Wv_bf = Wbf + 2 * 262144;
  unsigned short* Wo_bf = Wbf + 3 * 262144;
  unsigned short* Wl_bf = Wbf + 4 * 262144;
  unsigned short* Vt = (unsigned short*)(ws + 2621440);  // [512][768]
  char* big = ws + 3407872;
  unsigned short* Q_bf  = (unsigned short*)(big + 0);         // 4096x512
  unsigned short* K_bf  = (unsigned short*)(big + 4194304);   // 768x512
  unsigned short* S     = (unsigned short*)(big + 4980736);   // 2x4096x768
  unsigned short* tn_bf = (unsigned short*)(big + 17563648);  // 4096x512
  unsigned short* vn_bf = (unsigned short*)(big + 21757952);  // 768x512
  unsigned short* att_bf = tn_bf;                             // tn dead then
  float* Ob  = (float*)(big + 4980736);                       // over S (dead)
  float* o2f = (float*)(big + 13369344);                      // over S tail
  unsigned short* o2_bf = vn_bf;                              // vn dead then
  float* lin = (float*)(big + 0);                             // Q/K dead then
  int* sync = (int*)(ws + 29360128);

  int bid = blockIdx.x, tid = threadIdx.x;

  // ---- init latch: d_ws is poisoned 0xAA each launch; block 0 zeroes the
  // barrier slots, everyone else waits for MAGIC.
  if (bid == 0) {
    if (tid < 15) sync[tid] = 0;
    __syncthreads();
    if (tid == 0) {
      __threadfence();
      __hip_atomic_store(&sync[15], MAGIC, __ATOMIC_RELEASE,
                         __HIP_MEMORY_SCOPE_AGENT);
    }
    __syncthreads();
  } else {
    if (tid == 0)
      while (__hip_atomic_load(&sync[15], __ATOMIC_ACQUIRE,
                               __HIP_MEMORY_SCOPE_AGENT) != (int)MAGIC)
        __builtin_amdgcn_s_sleep(8);
    __syncthreads();
  }

  // ---- phase 0: weight cvt + LN1(text/video) ----
  {
    int gtid = bid * 512 + tid;
    for (int i = gtid; i < 327680; i += 131072) {
      const float* src = (i < 65536) ? Wq
                       : (i < 131072) ? Wk
                       : (i < 196608) ? Wv
                       : (i < 262144) ? Wo : Wl;
      float4 v = ((const float4*)src)[i & 65535];
      uint2 o;
      o.x = f2bf(v.x) | (f2bf(v.y) << 16);
      o.y = f2bf(v.z) | (f2bf(v.w) << 16);
      ((uint2*)Wbf)[i] = o;
    }
    float* sbuf = (float*)scratch;
    for (int it = 0; it < 19; ++it) {  // 4864 rows = 256*19
      int r = bid + it * 256;
      if (r < NT_TOK)
        ln_row512(text + (size_t)r * EMBED, nullptr, ln1_g, ln1_b, nullptr,
                  tn_bf + (size_t)r * EMBED, sbuf);
      else
        ln_row512(video + (size_t)(r - NT_TOK) * EMBED, nullptr, ln1_g, ln1_b,
                  nullptr, vn_bf + (size_t)(r - NT_TOK) * EMBED, sbuf);
    }
  }
  gbar(sync, 0);

  // ---- phase 1: QKV projections (V written pre-transposed) ----
  {
    int j = bid;
    if (j < 128) {
      int m0 = (j >> 2) * 128, n0 = (j & 3) * 128;
      gemm_tile<0>(tn_bf, EMBED, Wq_bf, EMBED, bq, Q_bf, EMBED, m0, n0, EMBED,
                   As, Bs);
    } else if (j < 152) {
      int i = j - 128;
      int m0 = (i >> 2) * 128, n0 = (i & 3) * 128;
      gemm_tile<0>(vn_bf, EMBED, Wk_bf, EMBED, bk, K_bf, EMBED, m0, n0, EMBED,
                   As, Bs);
    } else if (j < 176) {
      int i = j - 152;
      int m0 = (i >> 2) * 128, n0 = (i & 3) * 128;
      gemm_tile<2>(vn_bf, EMBED, Wv_bf, EMBED, bv, Vt, NV_TOK, m0, n0, EMBED,
                   As, Bs);
    }
  }
  gbar(sync, 1);

  // ---- phase 2: S[h] = Q_h @ K_h^T (384 tile jobs) ----
  for (int jj = bid; jj < 384; jj += 256) {
    int h = jj / 192, i = jj % 192;
    int m0 = (i / 6) * 128, n0 = (i % 6) * 128;
    gemm_tile<0>(Q_bf + h * HD, EMBED, K_bf + h * HD, EMBED, nullptr,
                 S + (size_t)h * NT_TOK * NV_TOK, NV_TOK, m0, n0, HD, As, Bs);
  }
  gbar(sync, 2);

  // ---- phase 3: in-place 12-group softmax (folds 1/16 and 1/64) ----
  {
    uint2* sb = (uint2*)scratch;  // 1536 uint2 = 12 KB
    for (int it = 0; it < 4; ++it) {
      int c = bid + it * 256;  // 1024 chunks of 512 groups
      uint2* gp = (uint2*)S + (size_t)c * 1536;
      __syncthreads();
      #pragma unroll
      for (int i = 0; i < 3; ++i) sb[tid + i * 512] = gp[tid + i * 512];
      __syncthreads();
      uint2 u0 = sb[tid * 3], u1 = sb[tid * 3 + 1], u2 = sb[tid * 3 + 2];
      float v[12];
      v[0] = bf2f(u0.x & 0xffff);  v[1] = bf2f(u0.x >> 16);
      v[2] = bf2f(u0.y & 0xffff);  v[3] = bf2f(u0.y >> 16);
      v[4] = bf2f(u1.x & 0xffff);  v[5] = bf2f(u1.x >> 16);
      v[6] = bf2f(u1.y & 0xffff);  v[7] = bf2f(u1.y >> 16);
      v[8] = bf2f(u2.x & 0xffff);  v[9] = bf2f(u2.x >> 16);
      v[10] = bf2f(u2.y & 0xffff); v[11] = bf2f(u2.y >> 16);
      float m = -1e30f;
      #pragma unroll
      for (int f = 0; f < FR; ++f) { v[f] *= 0.0625f; m = fmaxf(m, v[f]); }
      float s = 0.f;
      #pragma unroll
      for (int f = 0; f < FR; ++f) { v[f] = __expf(v[f] - m); s += v[f]; }
      float inv = (1.0f / NV) / s;
      unsigned int wv_[12];
      #pragma unroll
      for (int f = 0; f < FR; ++f) wv_[f] = f2bf(v[f] * inv);
      sb[tid * 3]     = (uint2){wv_[0] | (wv_[1] << 16), wv_[2] | (wv_[3] << 16)};
      sb[tid * 3 + 1] = (uint2){wv_[4] | (wv_[5] << 16), wv_[6] | (wv_[7] << 16)};
      sb[tid * 3 + 2] = (uint2){wv_[8] | (wv_[9] << 16), wv_[10] | (wv_[11] << 16)};
      __syncthreads();
      #pragma unroll
      for (int i = 0; i < 3; ++i) gp[tid + i * 512] = sb[tid + i * 512];
    }
  }
  gbar(sync, 3);

  // ---- phase 4: att[:, h*256+d] = P_h @ Vt_h^T (128 jobs) ----
  if (bid < 128) {
    int h = bid >> 6, i = bid & 63;
    int m0 = (i >> 1) * 128, n0 = (i & 1) * 128;
    gemm_tile<0>(S + (size_t)h * NT_TOK * NV_TOK, NV_TOK,
                 Vt + (size_t)h * HD * NV_TOK, NV_TOK, nullptr,
                 att_bf + h * HD, EMBED, m0, n0, NV_TOK, As, Bs);
  }
  gbar(sync, 4);

  // ---- phase 5: Ob = att @ Wo^T + bo (fp32 out) ----
  if (bid < 128) {
    int m0 = (bid >> 2) * 128, n0 = (bid & 3) * 128;
    gemm_tile<1>(att_bf, EMBED, Wo_bf, EMBED, bo, Ob, EMBED, m0, n0, EMBED,
                 As, Bs);
  }
  gbar(sync, 5);

  // ---- phase 6: LN2 ----
  {
    float* sbuf = (float*)scratch;
    for (int it = 0; it < 16; ++it) {
      int r = bid + it * 256;
      ln_row512(Ob + (size_t)r * EMBED, nullptr, ln2_g, ln2_b,
                o2f + (size_t)r * EMBED, o2_bf + (size_t)r * EMBED, sbuf);
    }
  }
  gbar(sync, 6);

  // ---- phase 7: lin = o2 @ Wl^T + bl (fp32 out) ----
  if (bid < 128) {
    int m0 = (bid >> 2) * 128, n0 = (bid & 3) * 128;
    gemm_tile<1>(o2_bf, EMBED, Wl_bf, EMBED, bl, lin, EMBED, m0, n0, EMBED,
                 As, Bs);
  }
  gbar(sync, 7);

  // ---- phase 8: LN3(o2 + lin) -> out ----
  {
    float* sbuf = (float*)scratch;
    for (int it = 0; it < 16; ++it) {
      int r = bid + it * 256;
      ln_row512(o2f + (size_t)r * EMBED, lin + (size_t)r * EMBED, ln3_g, ln3_b,
                out + (size_t)r * EMBED, nullptr, sbuf);
    }
  }
}

// ---- launch ---------------------------------------------------------------
extern "C" void kernel_launch(void* const* d_in, const int* in_sizes, int n_in,
                              void* d_out, int out_size, void* d_ws, size_t ws_size,
                              hipStream_t stream) {
  (void)in_sizes; (void)n_in; (void)out_size; (void)ws_size;
  mega<<<NBLK, 512, 0, stream>>>(
      (const float*)d_in[0], (const float*)d_in[1],
      (const float*)d_in[2], (const float*)d_in[3],
      (const float*)d_in[4], (const float*)d_in[5],
      (const float*)d_in[6], (const float*)d_in[7],
      (const float*)d_in[8], (const float*)d_in[9],
      (const float*)d_in[10], (const float*)d_in[11],
      (const float*)d_in[12], (const float*)d_in[13],
      (const float*)d_in[14], (const float*)d_in[15],
      (const float*)d_in[16], (const float*)d_in[17],
      (float*)d_out, (char*)d_ws);
}

// Round 7
// 162.733 us; speedup vs baseline: 3.1533x; 3.1533x over previous
//
#include <hip/hip_runtime.h>
#include <math.h>

#define EMBED 512
#define HD 256
#define FR 12
#define NV 64
#define NT_TOK 4096
#define NV_TOK 768

typedef __attribute__((ext_vector_type(8))) short short8;
typedef __attribute__((ext_vector_type(4))) float f32x4;

__device__ __forceinline__ unsigned int f2bf(float f) {
  unsigned int u = __float_as_uint(f);
  u += 0x7FFFu + ((u >> 16) & 1u);   // RNE
  return u >> 16;
}
__device__ __forceinline__ void async_cp16(void* lds, const void* g) {
  __builtin_amdgcn_global_load_lds(
      (const __attribute__((address_space(1))) void*)g,
      (__attribute__((address_space(3))) void*)lds, 16, 0, 0);
}

// ===== 64x64 GEMM core: BK=64, 4 waves of 32x32 ============================
// Double-buffered with ONE __syncthreads per iter (safe: syncthreads drains
// each wave's global_load_lds vmcnt before the barrier, so buf[cur] is fully
// resident and buf[cur^1] has no readers when the prefetch is issued).
// A: [M][lda] bf16 k-contig; B: [N][ldb] bf16 k-contig. XOR-swizzled LDS.
__device__ __forceinline__ void gemm64_core(
    const unsigned short* __restrict__ Ab, int lda,
    const unsigned short* __restrict__ Bb, int ldb,
    int m0, int n0, int K,
    unsigned short* __restrict__ As, unsigned short* __restrict__ Bs,
    f32x4 acc[2][2]) {
  int tid = threadIdx.x;
  int w = tid >> 6, lane = tid & 63;
  int lr = lane & 15, quad = lane >> 4;
  int wm = (w >> 1) * 32, wn = (w & 1) * 32;
  int rowS[2], cgS[2];
  #pragma unroll
  for (int i = 0; i < 2; ++i) {
    int s = tid + i * 256;
    rowS[i] = s >> 3; cgS[i] = (s & 7) ^ (rowS[i] & 7);
  }
  int nk = K >> 6;
  #pragma unroll
  for (int i = 0; i < 2; ++i) {
    async_cp16(&As[(tid + i * 256) * 8],
               Ab + (size_t)(m0 + rowS[i]) * lda + cgS[i] * 8);
    async_cp16(&Bs[(tid + i * 256) * 8],
               Bb + (size_t)(n0 + rowS[i]) * ldb + cgS[i] * 8);
  }
  for (int k = 0; k < nk; ++k) {
    int cur = k & 1;
    __syncthreads();  // buf[cur] resident everywhere; buf[cur^1] reader-free
    if (k + 1 < nk) {
      int nxt = cur ^ 1, koff = (k + 1) << 6;
      #pragma unroll
      for (int i = 0; i < 2; ++i) {
        async_cp16(&As[nxt * 4096 + (tid + i * 256) * 8],
                   Ab + (size_t)(m0 + rowS[i]) * lda + koff + cgS[i] * 8);
        async_cp16(&Bs[nxt * 4096 + (tid + i * 256) * 8],
                   Bb + (size_t)(n0 + rowS[i]) * ldb + koff + cgS[i] * 8);
      }
    }
    const unsigned short* Ac = As + cur * 4096;
    const unsigned short* Bc = Bs + cur * 4096;
    #pragma unroll
    for (int kk = 0; kk < 2; ++kk) {
      int sw = ((kk * 4 + quad) ^ (lr & 7)) * 8;
      short8 a0 = *(const short8*)&Ac[(wm + lr) * 64 + sw];
      short8 a1 = *(const short8*)&Ac[(wm + 16 + lr) * 64 + sw];
      short8 b0 = *(const short8*)&Bc[(wn + lr) * 64 + sw];
      short8 b1 = *(const short8*)&Bc[(wn + 16 + lr) * 64 + sw];
      acc[0][0] = __builtin_amdgcn_mfma_f32_16x16x32_bf16(a0, b0, acc[0][0], 0, 0, 0);
      acc[0][1] = __builtin_amdgcn_mfma_f32_16x16x32_bf16(a0, b1, acc[0][1], 0, 0, 0);
      acc[1][0] = __builtin_amdgcn_mfma_f32_16x16x32_bf16(a1, b0, acc[1][0], 0, 0, 0);
      acc[1][1] = __builtin_amdgcn_mfma_f32_16x16x32_bf16(a1, b1, acc[1][1], 0, 0, 0);
    }
  }
}

// ===== generic 64x64 GEMM kernel (PV / O / L) ==============================
template <int MODE, bool BIAS>  // MODE 0: bf16 out; 1: fp32 out
__global__ __launch_bounds__(256, 4) void gemm64(
    const unsigned short* __restrict__ A, int lda, long AzS,
    const unsigned short* __restrict__ B, int ldb, long BzS,
    const float* __restrict__ bias, void* __restrict__ Cv, int ldc, long CzS,
    int K) {
  __shared__ __align__(16) unsigned short As[2 * 4096];
  __shared__ __align__(16) unsigned short Bs[2 * 4096];
  f32x4 acc[2][2] = {};
  const unsigned short* Ab = A + (size_t)blockIdx.z * AzS;
  const unsigned short* Bb = B + (size_t)blockIdx.z * BzS;
  int m0 = blockIdx.x * 64, n0 = blockIdx.y * 64;
  gemm64_core(Ab, lda, Bb, ldb, m0, n0, K, As, Bs, acc);
  int w = threadIdx.x >> 6, lane = threadIdx.x & 63;
  int lr = lane & 15, quad = lane >> 4;
  int wm = (w >> 1) * 32, wn = (w & 1) * 32;
  long cz = (long)blockIdx.z * CzS;
  #pragma unroll
  for (int j = 0; j < 2; ++j) {
    int col = n0 + wn + j * 16 + lr;
    float bv = BIAS ? bias[col] : 0.0f;
    #pragma unroll
    for (int i = 0; i < 2; ++i) {
      int rbase = m0 + wm + i * 16 + quad * 4;
      #pragma unroll
      for (int r = 0; r < 4; ++r) {
        float v = acc[i][j][r] + bv;
        if (MODE == 0)
          ((unsigned short*)Cv)[cz + (size_t)(rbase + r) * ldc + col] =
              (unsigned short)f2bf(v);
        else
          ((float*)Cv)[cz + (size_t)(rbase + r) * ldc + col] = v;
      }
    }
  }
}

// ===== fused QKV projection (V written transposed) =========================
__global__ __launch_bounds__(256, 4) void qkv_kernel(
    const unsigned short* __restrict__ tn, const unsigned short* __restrict__ vn,
    const unsigned short* __restrict__ Wq, const unsigned short* __restrict__ Wk,
    const unsigned short* __restrict__ Wv,
    const float* __restrict__ bq, const float* __restrict__ bk,
    const float* __restrict__ bv,
    unsigned short* __restrict__ Q, unsigned short* __restrict__ Kout,
    unsigned short* __restrict__ Vt) {
  __shared__ __align__(16) unsigned short As[2 * 4096];
  __shared__ __align__(16) unsigned short Bs[2 * 4096];
  int bid = blockIdx.x;
  const unsigned short *Ap, *Bp;
  const float* bias;
  unsigned short* outp = nullptr;
  int m0, n0, mode;
  if (bid < 512) {            // Q: 64x8 tiles over 4096 rows
    Ap = tn; Bp = Wq; bias = bq; outp = Q;
    m0 = (bid >> 3) * 64; n0 = (bid & 7) * 64; mode = 0;
  } else if (bid < 608) {     // K: 12x8 tiles over 768 rows
    int i = bid - 512;
    Ap = vn; Bp = Wk; bias = bk; outp = Kout;
    m0 = (i >> 3) * 64; n0 = (i & 7) * 64; mode = 0;
  } else {                    // V -> Vt[d][t]
    int i = bid - 608;
    Ap = vn; Bp = Wv; bias = bv;
    m0 = (i >> 3) * 64; n0 = (i & 7) * 64; mode = 1;
  }
  f32x4 acc[2][2] = {};
  gemm64_core(Ap, EMBED, Bp, EMBED, m0, n0, EMBED, As, Bs, acc);
  int w = threadIdx.x >> 6, lane = threadIdx.x & 63;
  int lr = lane & 15, quad = lane >> 4;
  int wm = (w >> 1) * 32, wn = (w & 1) * 32;
  #pragma unroll
  for (int j = 0; j < 2; ++j) {
    int col = n0 + wn + j * 16 + lr;
    float bvv = bias[col];
    #pragma unroll
    for (int i = 0; i < 2; ++i) {
      int rbase = m0 + wm + i * 16 + quad * 4;
      if (mode == 0) {
        #pragma unroll
        for (int r = 0; r < 4; ++r)
          outp[(size_t)(rbase + r) * EMBED + col] =
              (unsigned short)f2bf(acc[i][j][r] + bvv);
      } else {
        ushort4 pk;
        pk.x = (unsigned short)f2bf(acc[i][j][0] + bvv);
        pk.y = (unsigned short)f2bf(acc[i][j][1] + bvv);
        pk.z = (unsigned short)f2bf(acc[i][j][2] + bvv);
        pk.w = (unsigned short)f2bf(acc[i][j][3] + bvv);
        *(ushort4*)&Vt[(size_t)col * NV_TOK + rbase] = pk;
      }
    }
  }
}

// ===== S-GEMM (64x96 tile) + in-epilogue 12-group softmax -> P bf16 ========
// N-tile 96 = 8 complete softmax groups (tile-local softmax). 1/16 logit
// scale and 1/64 batch-mean folded here (R4-proven numeric form).
__global__ __launch_bounds__(256, 4) void sgemm_softmax(
    const unsigned short* __restrict__ Q, const unsigned short* __restrict__ Kb,
    unsigned short* __restrict__ P) {
  __shared__ __align__(16) char smem[40960];  // As 16K | Bs 24K ; reused as Sx
  unsigned short* As = (unsigned short*)smem;            // 2 x 4096
  unsigned short* Bs = (unsigned short*)(smem + 16384);  // 2 x 6144
  int tid = threadIdx.x;
  int w = tid >> 6, lane = tid & 63;
  int lr = lane & 15, quad = lane >> 4;
  int wm = (w >> 1) * 32, wn = (w & 1) * 48;
  int h = blockIdx.z;
  int m0 = blockIdx.x * 64, n0 = blockIdx.y * 96;
  const unsigned short* Ab = Q + h * HD;
  const unsigned short* Bb = Kb + h * HD;
  int rowA[2], cgA[2], rowB[3], cgB[3];
  #pragma unroll
  for (int i = 0; i < 2; ++i) {
    int s = tid + i * 256;
    rowA[i] = s >> 3; cgA[i] = (s & 7) ^ (rowA[i] & 7);
  }
  #pragma unroll
  for (int i = 0; i < 3; ++i) {
    int s = tid + i * 256;
    rowB[i] = s >> 3; cgB[i] = (s & 7) ^ (rowB[i] & 7);
  }
  f32x4 acc[2][3] = {};
  const int nk = HD >> 6;  // 4
  #pragma unroll
  for (int i = 0; i < 2; ++i)
    async_cp16(&As[(tid + i * 256) * 8],
               Ab + (size_t)(m0 + rowA[i]) * EMBED + cgA[i] * 8);
  #pragma unroll
  for (int i = 0; i < 3; ++i)
    async_cp16(&Bs[(tid + i * 256) * 8],
               Bb + (size_t)(n0 + rowB[i]) * EMBED + cgB[i] * 8);
  for (int k = 0; k < nk; ++k) {
    int cur = k & 1;
    __syncthreads();
    if (k + 1 < nk) {
      int nxt = cur ^ 1, koff = (k + 1) << 6;
      #pragma unroll
      for (int i = 0; i < 2; ++i)
        async_cp16(&As[nxt * 4096 + (tid + i * 256) * 8],
                   Ab + (size_t)(m0 + rowA[i]) * EMBED + koff + cgA[i] * 8);
      #pragma unroll
      for (int i = 0; i < 3; ++i)
        async_cp16(&Bs[nxt * 6144 + (tid + i * 256) * 8],
                   Bb + (size_t)(n0 + rowB[i]) * EMBED + koff + cgB[i] * 8);
    }
    const unsigned short* Ac = As + cur * 4096;
    const unsigned short* Bc = Bs + cur * 6144;
    #pragma unroll
    for (int kk = 0; kk < 2; ++kk) {
      int sw = ((kk * 4 + quad) ^ (lr & 7)) * 8;
      short8 a0 = *(const short8*)&Ac[(wm + lr) * 64 + sw];
      short8 a1 = *(const short8*)&Ac[(wm + 16 + lr) * 64 + sw];
      short8 b0 = *(const short8*)&Bc[(wn + lr) * 64 + sw];
      short8 b1 = *(const short8*)&Bc[(wn + 16 + lr) * 64 + sw];
      short8 b2 = *(const short8*)&Bc[(wn + 32 + lr) * 64 + sw];
      acc[0][0] = __builtin_amdgcn_mfma_f32_16x16x32_bf16(a0, b0, acc[0][0], 0, 0, 0);
      acc[0][1] = __builtin_amdgcn_mfma_f32_16x16x32_bf16(a0, b1, acc[0][1], 0, 0, 0);
      acc[0][2] = __builtin_amdgcn_mfma_f32_16x16x32_bf16(a0, b2, acc[0][2], 0, 0, 0);
      acc[1][0] = __builtin_amdgcn_mfma_f32_16x16x32_bf16(a1, b0, acc[1][0], 0, 0, 0);
      acc[1][1] = __builtin_amdgcn_mfma_f32_16x16x32_bf16(a1, b1, acc[1][1], 0, 0, 0);
      acc[1][2] = __builtin_amdgcn_mfma_f32_16x16x32_bf16(a1, b2, acc[1][2], 0, 0, 0);
    }
  }
  // ---- epilogue: S tile -> LDS, per-group softmax, P bf16 to global ----
  __syncthreads();
  float* Sx = (float*)smem;  // [64][100] padded
  #pragma unroll
  for (int j = 0; j < 3; ++j) {
    int col = wn + j * 16 + lr;
    #pragma unroll
    for (int i = 0; i < 2; ++i) {
      int rbase = wm + i * 16 + quad * 4;
      #pragma unroll
      for (int r = 0; r < 4; ++r) Sx[(rbase + r) * 100 + col] = acc[i][j][r];
    }
  }
  __syncthreads();
  unsigned short* Ph = P + (size_t)h * NT_TOK * NV_TOK;
  #pragma unroll
  for (int gi = 0; gi < 2; ++gi) {
    int g = tid * 2 + gi;            // 512 groups: 64 rows x 8
    int row = g >> 3, gr = g & 7;
    const float* sp = Sx + row * 100 + gr * 12;
    float v[12];
    float m = -1e30f;
    #pragma unroll
    for (int f = 0; f < FR; ++f) { v[f] = sp[f] * 0.0625f; m = fmaxf(m, v[f]); }
    float s = 0.f;
    #pragma unroll
    for (int f = 0; f < FR; ++f) { v[f] = __expf(v[f] - m); s += v[f]; }
    float inv = (1.0f / NV) / s;
    unsigned short* pp = Ph + (size_t)(m0 + row) * NV_TOK + n0 + gr * 12;
    #pragma unroll
    for (int ii = 0; ii < 6; ++ii) {
      unsigned int lo = f2bf(v[2 * ii] * inv), hi = f2bf(v[2 * ii + 1] * inv);
      *(unsigned int*)(pp + 2 * ii) = lo | (hi << 16);
    }
  }
}

// ===== LayerNorm (256 thr, 2 elems each) ===================================
__device__ __forceinline__ void ln_row(
    const float* __restrict__ xr, const float* __restrict__ rr,
    const float* __restrict__ g, const float* __restrict__ b,
    float* __restrict__ outf, unsigned short* __restrict__ outb) {
  int t = threadIdx.x;
  float v0 = xr[t], v1 = xr[t + 256];
  if (rr != nullptr) { v0 += rr[t]; v1 += rr[t + 256]; }
  float s = v0 + v1;
  float s2 = v0 * v0 + v1 * v1;
  #pragma unroll
  for (int off = 32; off > 0; off >>= 1) {
    s += __shfl_down(s, off, 64);
    s2 += __shfl_down(s2, off, 64);
  }
  __shared__ float ss[4], ss2[4];
  __shared__ float mean_s, rstd_s;
  int wid = t >> 6;
  if ((t & 63) == 0) { ss[wid] = s; ss2[wid] = s2; }
  __syncthreads();
  if (t == 0) {
    float a = ss[0] + ss[1] + ss[2] + ss[3];
    float a2 = ss2[0] + ss2[1] + ss2[2] + ss2[3];
    float mean = a * (1.0f / EMBED);
    float var = a2 * (1.0f / EMBED) - mean * mean;
    mean_s = mean;
    rstd_s = rsqrtf(var + 1e-5f);
  }
  __syncthreads();
  float mean = mean_s, rstd = rstd_s;
  float y0 = (v0 - mean) * rstd * g[t] + b[t];
  float y1 = (v1 - mean) * rstd * g[t + 256] + b[t + 256];
  if (outf != nullptr) { outf[t] = y0; outf[t + 256] = y1; }
  if (outb != nullptr) {
    outb[t] = (unsigned short)f2bf(y0);
    outb[t + 256] = (unsigned short)f2bf(y1);
  }
}

__global__ __launch_bounds__(256) void ln_kernel(
    const float* __restrict__ x, const float* __restrict__ res,
    const float* __restrict__ g, const float* __restrict__ b,
    float* __restrict__ outf, unsigned short* __restrict__ outb) {
  size_t row = blockIdx.x;
  ln_row(x + row * EMBED, res ? res + row * EMBED : nullptr, g, b,
         outf ? outf + row * EMBED : nullptr,
         outb ? outb + row * EMBED : nullptr);
}

// ===== prep: weight fp32->bf16 + LN1 on text & video =======================
__global__ __launch_bounds__(256) void prep_kernel(
    const float* __restrict__ text, const float* __restrict__ video,
    const float* __restrict__ g, const float* __restrict__ b,
    const float* __restrict__ Wq, const float* __restrict__ Wk,
    const float* __restrict__ Wv, const float* __restrict__ Wo,
    const float* __restrict__ Wl, unsigned short* __restrict__ Wbf,
    unsigned short* __restrict__ tn, unsigned short* __restrict__ vn) {
  int bid = blockIdx.x;
  if (bid < 1280) {
    int i = bid * 256 + threadIdx.x;
    const float* srcs[5] = {Wq, Wk, Wv, Wo, Wl};
    const float* src = srcs[i >> 16];
    float4 v = ((const float4*)src)[i & 65535];
    uint2 o;
    o.x = f2bf(v.x) | (f2bf(v.y) << 16);
    o.y = f2bf(v.z) | (f2bf(v.w) << 16);
    ((uint2*)Wbf)[i] = o;
    return;
  }
  if (bid < 1280 + NT_TOK) {
    size_t row = bid - 1280;
    ln_row(text + row * EMBED, nullptr, g, b, nullptr, tn + row * EMBED);
  } else {
    size_t row = bid - (1280 + NT_TOK);
    ln_row(video + row * EMBED, nullptr, g, b, nullptr, vn + row * EMBED);
  }
}

// ===== launch ==============================================================
extern "C" void kernel_launch(void* const* d_in, const int* in_sizes, int n_in,
                              void* d_out, int out_size, void* d_ws, size_t ws_size,
                              hipStream_t stream) {
  (void)in_sizes; (void)n_in; (void)out_size; (void)ws_size;
  const float* text  = (const float*)d_in[0];
  const float* video = (const float*)d_in[1];
  const float* ln1_g = (const float*)d_in[2];
  const float* ln1_b = (const float*)d_in[3];
  const float* Wq = (const float*)d_in[4];
  const float* bq = (const float*)d_in[5];
  const float* Wk = (const float*)d_in[6];
  const float* bk = (const float*)d_in[7];
  const float* Wv = (const float*)d_in[8];
  const float* bv = (const float*)d_in[9];
  const float* Wo = (const float*)d_in[10];
  const float* bo = (const float*)d_in[11];
  const float* Wl = (const float*)d_in[12];
  const float* bl = (const float*)d_in[13];
  const float* ln2_g = (const float*)d_in[14];
  const float* ln2_b = (const float*)d_in[15];
  const float* ln3_g = (const float*)d_in[16];
  const float* ln3_b = (const float*)d_in[17];
  float* out = (float*)d_out;

  // ---- workspace (~26 MB, aliased phase-by-phase) ----
  char* base = (char*)d_ws;
  unsigned short* Wbf   = (unsigned short*)base;
  unsigned short* Wq_bf = Wbf + 0 * 262144;
  unsigned short* Wk_bf = Wbf + 1 * 262144;
  unsigned short* Wv_bf = Wbf + 2 * 262144;
  unsigned short* Wo_bf = Wbf + 3 * 262144;
  unsigned short* Wl_bf = Wbf + 4 * 262144;
  unsigned short* Vt    = (unsigned short*)(base + 2621440);  // [512][768]
  char* big = base + 3407872;
  unsigned short* Q_bf  = (unsigned short*)(big + 0);         // 4096x512
  unsigned short* K_bf  = (unsigned short*)(big + 4194304);   // 768x512
  unsigned short* P     = (unsigned short*)(big + 4980736);   // 2x4096x768
  unsigned short* tn_bf = (unsigned short*)(big + 17563648);  // 4096x512
  unsigned short* vn_bf = (unsigned short*)(big + 21757952);  // 768x512
  unsigned short* att_bf = tn_bf;                             // tn dead then
  float* Ob  = (float*)(big + 4980736);                       // over P (dead)
  float* o2f = (float*)(big + 13369344);                      // over P tail/att
  unsigned short* o2_bf = vn_bf;                              // vn dead then
  float* lin = (float*)(big + 0);                             // Q/K dead then

  prep_kernel<<<1280 + NT_TOK + NV_TOK, 256, 0, stream>>>(
      text, video, ln1_g, ln1_b, Wq, Wk, Wv, Wo, Wl, Wbf, tn_bf, vn_bf);

  qkv_kernel<<<704, 256, 0, stream>>>(tn_bf, vn_bf, Wq_bf, Wk_bf, Wv_bf,
                                      bq, bk, bv, Q_bf, K_bf, Vt);

  // P[h] = softmax_12(Q_h @ K_h^T / 16) / 64, 64x96 tiles
  sgemm_softmax<<<dim3(64, 8, 2), 256, 0, stream>>>(Q_bf, K_bf, P);

  // att[:, h*256+d] = P_h @ Vt_h^T
  gemm64<0, false><<<dim3(64, 4, 2), 256, 0, stream>>>(
      P, NV_TOK, (long)NT_TOK * NV_TOK, Vt, NV_TOK, (long)HD * NV_TOK, nullptr,
      att_bf, EMBED, HD, NV_TOK);

  gemm64<1, true><<<dim3(64, 8, 1), 256, 0, stream>>>(
      att_bf, EMBED, 0, Wo_bf, EMBED, 0, bo, Ob, EMBED, 0, EMBED);
  ln_kernel<<<NT_TOK, 256, 0, stream>>>(Ob, nullptr, ln2_g, ln2_b, o2f, o2_bf);
  gemm64<1, true><<<dim3(64, 8, 1), 256, 0, stream>>>(
      o2_bf, EMBED, 0, Wl_bf, EMBED, 0, bl, lin, EMBED, 0, EMBED);
  ln_kernel<<<NT_TOK, 256, 0, stream>>>(o2f, lin, ln3_g, ln3_b, out, nullptr);
}